// Round 1
// baseline (6492.272 us; speedup 1.0000x reference)
//
#include <hip/hip_runtime.h>
#include <math.h>

#define N_NODES 100000
#define N_EDGES 1600000

// ---------------------------------------------------------------------------
// Node projections: Q,K,V,G = x @ W.T (+bias for G). One node per lane,
// weights read as wave-uniform scalars (s_load), x row in registers.
// Q stored [N][64]; K,V,G packed as SRC[N][192] for gather locality.
// ---------------------------------------------------------------------------
__global__ __launch_bounds__(256) void k_node_proj(
    const float* __restrict__ x,
    const float* __restrict__ WQ, const float* __restrict__ WK,
    const float* __restrict__ WV, const float* __restrict__ NG,
    const float* __restrict__ NGb,
    float* __restrict__ Qout, float* __restrict__ SRCout)
{
    int n = blockIdx.x * 256 + threadIdx.x;
    if (n >= N_NODES) return;

    float xr[64];
    const float4* xp = reinterpret_cast<const float4*>(x + (size_t)n * 64);
#pragma unroll
    for (int i = 0; i < 16; ++i) {
        float4 v = xp[i];
        xr[4*i+0] = v.x; xr[4*i+1] = v.y; xr[4*i+2] = v.z; xr[4*i+3] = v.w;
    }

    float4* qo = reinterpret_cast<float4*>(Qout + (size_t)n * 64);
    float4* so = reinterpret_cast<float4*>(SRCout + (size_t)n * 192);

    for (int o4 = 0; o4 < 16; ++o4) {
        float q[4] = {0.f,0.f,0.f,0.f};
        float k[4] = {0.f,0.f,0.f,0.f};
        float v[4] = {0.f,0.f,0.f,0.f};
        float g[4];
#pragma unroll
        for (int s = 0; s < 4; ++s) g[s] = NGb[o4*4+s];
#pragma unroll
        for (int j = 0; j < 64; ++j) {
            float xj = xr[j];
#pragma unroll
            for (int s = 0; s < 4; ++s) {
                int row = o4*4 + s;
                q[s] = fmaf(WQ[row*64+j], xj, q[s]);
                k[s] = fmaf(WK[row*64+j], xj, k[s]);
                v[s] = fmaf(WV[row*64+j], xj, v[s]);
                g[s] = fmaf(NG[row*64+j], xj, g[s]);
            }
        }
        qo[o4]      = make_float4(q[0], q[1], q[2], q[3]);
        so[o4]      = make_float4(k[0], k[1], k[2], k[3]);   // K @ [0,64)
        so[16+o4]   = make_float4(v[0], v[1], v[2], v[3]);   // V @ [64,128)
        so[32+o4]   = make_float4(g[0], g[1], g[2], g[3]);   // G @ [128,192)
    }
}

// ---------------------------------------------------------------------------
// Tiny prep: transpose WO, ffn_w1, ffn_w2 (64x64 each) for the node-final
// wave-per-node GEMVs (coalesced lane-indexed weight reads).
// ---------------------------------------------------------------------------
__global__ void k_transpose3(const float* __restrict__ A,
                             const float* __restrict__ B,
                             const float* __restrict__ C,
                             float* __restrict__ T)
{
    int m = blockIdx.x;
    const float* W = (m == 0) ? A : ((m == 1) ? B : C);
    float* O = T + (size_t)m * 4096;
    for (int k = threadIdx.x; k < 4096; k += 256) {
        int j = k >> 6, o = k & 63;
        O[k] = W[o*64 + j];   // O[j][o] = W[o][j]
    }
}

// ---------------------------------------------------------------------------
// Fused edge pass: one edge per lane.
//  - Ef/Eg GEMVs (32->64) with scalar weights
//  - qijk, logits, ex=exp(logit)  (segment-max skipped: alpha is invariant)
//  - atomicAdd ex into sden[dst][h], ex*gate*V into agg[dst][:]
//  - full edge update (WOe GEMV + LN + FFN + LN) -> eout
// ---------------------------------------------------------------------------
__global__ __launch_bounds__(256) void k_edge(
    const float* __restrict__ ea_g,
    const int*   __restrict__ ei,
    const float* __restrict__ Q,   const float* __restrict__ SRC,
    const float* __restrict__ WE,  const float* __restrict__ WEb,
    const float* __restrict__ EG,  const float* __restrict__ EGb,
    const float* __restrict__ WOe, const float* __restrict__ WOeb,
    const float* __restrict__ W1,  const float* __restrict__ W1b,
    const float* __restrict__ W2,  const float* __restrict__ W2b,
    const float* __restrict__ g1,  const float* __restrict__ b1,
    const float* __restrict__ g2,  const float* __restrict__ b2,
    float* __restrict__ sden, float* __restrict__ agg,
    float* __restrict__ eout)
{
    int e = blockIdx.x * 256 + threadIdx.x;   // N_EDGES % 256 == 0
    int src = ei[e];
    int dst = ei[N_EDGES + e];

    float ea[32];
    {
        const float4* eap = reinterpret_cast<const float4*>(ea_g + (size_t)e * 32);
#pragma unroll
        for (int i = 0; i < 8; ++i) {
            float4 t = eap[i];
            ea[4*i+0] = t.x; ea[4*i+1] = t.y; ea[4*i+2] = t.z; ea[4*i+3] = t.w;
        }
    }

    float emid[32];
#pragma unroll
    for (int j = 0; j < 32; ++j) emid[j] = 0.f;

    const float4* Qbase = reinterpret_cast<const float4*>(Q + (size_t)dst * 64);
    const float4* Sbase = reinterpret_cast<const float4*>(SRC + (size_t)src * 192);

    for (int h = 0; h < 4; ++h) {
        float Qd[16], Ks[16];
#pragma unroll
        for (int i = 0; i < 4; ++i) {
            float4 a = Qbase[h*4 + i];
            Qd[4*i+0]=a.x; Qd[4*i+1]=a.y; Qd[4*i+2]=a.z; Qd[4*i+3]=a.w;
            float4 b = Sbase[h*4 + i];
            Ks[4*i+0]=b.x; Ks[4*i+1]=b.y; Ks[4*i+2]=b.z; Ks[4*i+3]=b.w;
        }

        float qk[16];
        float logit = 0.f;
#pragma unroll
        for (int o = 0; o < 16; ++o) {
            float ef = WEb[h*16 + o];
#pragma unroll
            for (int j = 0; j < 32; ++j)
                ef = fmaf(WE[(h*16+o)*32 + j], ea[j], ef);
            float t = Qd[o] * Ks[o] * ef * 0.25f;
            qk[o] = t;
            logit += t;
        }

        float ex = __expf(logit);
        atomicAdd(&sden[(size_t)dst*4 + h], ex);

        // WOe accumulation (edge message path)
#pragma unroll
        for (int o = 0; o < 16; ++o) {
            float t = qk[o];
#pragma unroll
            for (int j = 0; j < 32; ++j)
                emid[j] = fmaf(WOe[j*64 + h*16 + o], t, emid[j]);
        }

        // gated value message
        float Vs[16], Gs[16];
#pragma unroll
        for (int i = 0; i < 4; ++i) {
            float4 a = Sbase[16 + h*4 + i];   // V @ [64,128)
            Vs[4*i+0]=a.x; Vs[4*i+1]=a.y; Vs[4*i+2]=a.z; Vs[4*i+3]=a.w;
            float4 b = Sbase[32 + h*4 + i];   // G @ [128,192)
            Gs[4*i+0]=b.x; Gs[4*i+1]=b.y; Gs[4*i+2]=b.z; Gs[4*i+3]=b.w;
        }
#pragma unroll
        for (int o = 0; o < 16; ++o) {
            float eg = EGb[h*16 + o];
#pragma unroll
            for (int j = 0; j < 32; ++j)
                eg = fmaf(EG[(h*16+o)*32 + j], ea[j], eg);
            float gate = 1.f / (1.f + __expf(-(Gs[o] + eg)));
            atomicAdd(&agg[(size_t)dst*64 + h*16 + o], ex * gate * Vs[o]);
        }
    }

    // ---- edge update epilogue (pure per-lane) ----
    float y[32];
    {
        float mean = 0.f;
#pragma unroll
        for (int j = 0; j < 32; ++j) {
            float t = emid[j] + WOeb[j] + ea[j];
            y[j] = t;
            mean += t;
        }
        mean *= (1.f/32.f);
        float var = 0.f;
#pragma unroll
        for (int j = 0; j < 32; ++j) { float d = y[j]-mean; var = fmaf(d,d,var); }
        var *= (1.f/32.f);
        float rs = rsqrtf(var + 1e-5f);
#pragma unroll
        for (int j = 0; j < 32; ++j)
            y[j] = (y[j]-mean)*rs*g1[j] + b1[j];
    }

    float ff[32];
#pragma unroll
    for (int j = 0; j < 32; ++j) ff[j] = W2b[j];
    for (int k = 0; k < 64; ++k) {
        float hk = W1b[k];
#pragma unroll
        for (int j = 0; j < 32; ++j)
            hk = fmaf(W1[k*32 + j], y[j], hk);
        hk = fmaxf(hk, 0.f);
#pragma unroll
        for (int j = 0; j < 32; ++j)
            ff[j] = fmaf(W2[j*64 + k], hk, ff[j]);
    }

    {
        float mean = 0.f;
#pragma unroll
        for (int j = 0; j < 32; ++j) { ff[j] += y[j]; mean += ff[j]; }
        mean *= (1.f/32.f);
        float var = 0.f;
#pragma unroll
        for (int j = 0; j < 32; ++j) { float d = ff[j]-mean; var = fmaf(d,d,var); }
        var *= (1.f/32.f);
        float rs = rsqrtf(var + 1e-5f);
#pragma unroll
        for (int j = 0; j < 32; ++j)
            ff[j] = (ff[j]-mean)*rs*g2[j] + b2[j];
    }

    float4* op = reinterpret_cast<float4*>(eout + (size_t)e * 32);
#pragma unroll
    for (int i = 0; i < 8; ++i)
        op[i] = make_float4(ff[4*i+0], ff[4*i+1], ff[4*i+2], ff[4*i+3]);
}

// ---------------------------------------------------------------------------
// Node finalization: wave per node. Normalize agg by sden, WO GEMV + residual,
// LN, FFN, LN. Row lives across lanes; __shfl broadcast for dot products.
// ---------------------------------------------------------------------------
__global__ __launch_bounds__(256) void k_node_final(
    const float* __restrict__ agg, const float* __restrict__ sden,
    const float* __restrict__ x,
    const float* __restrict__ WOT, const float* __restrict__ WOb,
    const float* __restrict__ W1T, const float* __restrict__ W1b,
    const float* __restrict__ W2T, const float* __restrict__ W2b,
    const float* __restrict__ g1,  const float* __restrict__ b1,
    const float* __restrict__ g2,  const float* __restrict__ b2,
    float* __restrict__ outp)
{
    int gid  = blockIdx.x * 256 + threadIdx.x;
    int n    = gid >> 6;
    int lane = threadIdx.x & 63;
    if (n >= N_NODES) return;

    float a = agg[(size_t)n*64 + lane] / (sden[(size_t)n*4 + (lane>>4)] + 1e-16f);

    float acc = WOb[lane] + x[(size_t)n*64 + lane];
    for (int j = 0; j < 64; ++j)
        acc = fmaf(WOT[j*64 + lane], __shfl(a, j), acc);

    // LN1
    float s = acc;
    for (int off = 32; off; off >>= 1) s += __shfl_xor(s, off);
    float mean = s * (1.f/64.f);
    float d = acc - mean;
    float vs = d*d;
    for (int off = 32; off; off >>= 1) vs += __shfl_xor(vs, off);
    float rs = rsqrtf(vs*(1.f/64.f) + 1e-5f);
    float yv = d*rs*g1[lane] + b1[lane];

    // FFN
    float hk = W1b[lane];
    for (int j = 0; j < 64; ++j)
        hk = fmaf(W1T[j*64 + lane], __shfl(yv, j), hk);
    hk = fmaxf(hk, 0.f);
    float fo = W2b[lane];
    for (int k = 0; k < 64; ++k)
        fo = fmaf(W2T[k*64 + lane], __shfl(hk, k), fo);

    float u = yv + fo;
    // LN2
    float s2 = u;
    for (int off = 32; off; off >>= 1) s2 += __shfl_xor(s2, off);
    float mean2 = s2 * (1.f/64.f);
    float d2 = u - mean2;
    float v2 = d2*d2;
    for (int off = 32; off; off >>= 1) v2 += __shfl_xor(v2, off);
    float rs2 = rsqrtf(v2*(1.f/64.f) + 1e-5f);

    outp[(size_t)n*64 + lane] = d2*rs2*g2[lane] + b2[lane];
}

// ---------------------------------------------------------------------------
extern "C" void kernel_launch(void* const* d_in, const int* in_sizes, int n_in,
                              void* d_out, int out_size, void* d_ws, size_t ws_size,
                              hipStream_t stream)
{
    const float* x    = (const float*)d_in[0];
    const float* ea   = (const float*)d_in[1];
    const float* WQ   = (const float*)d_in[2];
    const float* WK   = (const float*)d_in[3];
    const float* WV   = (const float*)d_in[4];
    const float* WO   = (const float*)d_in[5];
    const float* WOb  = (const float*)d_in[6];
    const float* WE   = (const float*)d_in[7];
    const float* WEb  = (const float*)d_in[8];
    const float* WOe  = (const float*)d_in[9];
    const float* WOeb = (const float*)d_in[10];
    const float* NG   = (const float*)d_in[11];
    const float* NGb  = (const float*)d_in[12];
    const float* EGw  = (const float*)d_in[13];
    const float* EGb  = (const float*)d_in[14];
    const float* F1   = (const float*)d_in[15];
    const float* F1b  = (const float*)d_in[16];
    const float* F2   = (const float*)d_in[17];
    const float* F2b  = (const float*)d_in[18];
    const float* FE1  = (const float*)d_in[19];
    const float* FE1b = (const float*)d_in[20];
    const float* FE2  = (const float*)d_in[21];
    const float* FE2b = (const float*)d_in[22];
    const float* n1g  = (const float*)d_in[23];
    const float* n1b  = (const float*)d_in[24];
    const float* n2g  = (const float*)d_in[25];
    const float* n2b  = (const float*)d_in[26];
    const float* n1eg = (const float*)d_in[27];
    const float* n1eb = (const float*)d_in[28];
    const float* n2eg = (const float*)d_in[29];
    const float* n2eb = (const float*)d_in[30];
    const int*   ei   = (const int*)d_in[31];

    float* ws   = (float*)d_ws;
    float* sden = ws;                                    // N*4
    float* agg  = ws + (size_t)N_NODES * 4;              // N*64
    float* Q    = agg + (size_t)N_NODES * 64;            // N*64
    float* SRC  = Q + (size_t)N_NODES * 64;              // N*192
    float* TW   = SRC + (size_t)N_NODES * 192;           // 3*4096

    float* out_nodes = (float*)d_out;                    // N*64
    float* out_edges = out_nodes + (size_t)N_NODES * 64; // NE*32

    // zero sden + agg (contiguous)
    hipMemsetAsync(sden, 0, (size_t)N_NODES * 68 * sizeof(float), stream);

    k_transpose3<<<3, 256, 0, stream>>>(WO, F1, F2, TW);

    k_node_proj<<<(N_NODES + 255) / 256, 256, 0, stream>>>(
        x, WQ, WK, WV, NG, NGb, Q, SRC);

    k_edge<<<N_EDGES / 256, 256, 0, stream>>>(
        ea, ei, Q, SRC,
        WE, WEb, EGw, EGb, WOe, WOeb,
        FE1, FE1b, FE2, FE2b,
        n1eg, n1eb, n2eg, n2eb,
        sden, agg, out_edges);

    k_node_final<<<(N_NODES * 64 + 255) / 256, 256, 0, stream>>>(
        agg, sden, x,
        TW, WOb, TW + 4096, F1b, TW + 8192, F2b,
        n1g, n1b, n2g, n2b,
        out_nodes);
}